// Round 5
// baseline (1082.568 us; speedup 1.0000x reference)
//
#include <hip/hip_runtime.h>

typedef __attribute__((ext_vector_type(8))) short short8;
typedef __attribute__((ext_vector_type(4))) float float4v;

#define K_DIM 4096
#define O_DIM 11008
#define KP    2048   // packed int32 per output row
#define NBLK  64     // absmax blocks per row
#define BM    128
#define BN    128
#define BK    64
#define LDT   72     // padded LDS row stride in bf16 elems (144 B)

// NF4 table via immediate-literal select tree (no device globals).
__device__ __forceinline__ float nf4_val(int c) {
    float v = -1.0f;
    v = (c == 1)  ? -0.6961928009986877f   : v;
    v = (c == 2)  ? -0.5250730514526367f   : v;
    v = (c == 3)  ? -0.39491748809814453f  : v;
    v = (c == 4)  ? -0.28444138169288635f  : v;
    v = (c == 5)  ? -0.18477343022823334f  : v;
    v = (c == 6)  ? -0.09105003625154495f  : v;
    v = (c == 7)  ? 0.0f                   : v;
    v = (c == 8)  ? 0.07958029955625534f   : v;
    v = (c == 9)  ? 0.16093020141124725f   : v;
    v = (c == 10) ? 0.24611230194568634f   : v;
    v = (c == 11) ? 0.33791524171829224f   : v;
    v = (c == 12) ? 0.44070982933044434f   : v;
    v = (c == 13) ? 0.5626170039176941f    : v;
    v = (c == 14) ? 0.8072066307067871f    : v;
    v = (c == 15) ? 1.0f                   : v;
    return v;
}

__device__ __forceinline__ unsigned short bf16_rne(float f) {
    unsigned int u = __float_as_uint(f);
    u = (u + 0x7FFFu + ((u >> 16) & 1u)) >> 16;
    return (unsigned short)u;
}

__device__ __forceinline__ unsigned int pack_bf16x2(float lo_k, float hi_k) {
    // halfword0 (low) = smaller k index (little-endian LDS layout)
    return (unsigned int)bf16_rne(lo_k) | ((unsigned int)bf16_rne(hi_k) << 16);
}

__global__ __launch_bounds__(256) void nf4_linear_kernel(
    const float* __restrict__ X,              // f32 [M][4096]  (harness upcasts f16->f32)
    const int* __restrict__ Wp,               // [11008][2048] byte codes in int32
    const float* __restrict__ Smax,           // [11008][64]
    const float* __restrict__ Bias,           // f32 [11008]    (harness upcasts f16->f32)
    float* __restrict__ Out,                  // f32 [M][11008] (f16 output -> f32!)
    int M)
{
    __shared__ unsigned short Atile[BM * LDT];   // 18432 B
    __shared__ unsigned short Btile[BN * LDT];   // 18432 B
    __shared__ unsigned int   T2[256];           // byte -> packed bf16 pair (1 KB)

    const int t = threadIdx.x;
    const int m0 = blockIdx.x * BM;   // m fastest: 32 consecutive blocks share B-slab (L2 reuse)
    const int n0 = blockIdx.y * BN;

    // byte -> (bf16(NF4[hi nibble]) | bf16(NF4[lo nibble]) << 16); k-even = hi nibble = low half.
    {
        unsigned int hi = (unsigned int)bf16_rne(nf4_val(t >> 4));
        unsigned int lo = (unsigned int)bf16_rne(nf4_val(t & 15));
        T2[t] = hi | (lo << 16);
    }
    __syncthreads();

    const int lane = t & 63;
    const int wave = t >> 6;
    const int wm = (wave >> 1) * 64;     // wave tile row offset (m)
    const int wn = (wave & 1) * 64;      // wave tile col offset (n)
    const int ar = t >> 3;               // staging row base (0..31), +32 per i
    const int ach = t & 7;               // 8-elem chunk within row (0..7)

    float4v acc[4][4] = {};

    for (int s = 0; s < K_DIM / BK; ++s) {
        const int kt = s * BK;

        // ---- global loads for this stage ----
        float4v a0[4], a1[4]; uint4 wL[4]; float sc[4];
#pragma unroll
        for (int i = 0; i < 4; ++i) {
            const int row = ar + 32 * i;
            const float* ap = X + (size_t)(m0 + row) * K_DIM + kt + ach * 8;
            a0[i] = *(const float4v*)ap;
            a1[i] = *(const float4v*)(ap + 4);
            wL[i] = *(const uint4*)(Wp + (size_t)(n0 + row) * KP + (kt >> 1) + ach * 4);
            sc[i] = Smax[(n0 + row) * NBLK + s];
        }

        // ---- stage into LDS (A f32 -> bf16, B dequantized) ----
#pragma unroll
        for (int i = 0; i < 4; ++i) {
            const int row = ar + 32 * i;
            uint4 av;
            av.x = pack_bf16x2(a0[i].x, a0[i].y);
            av.y = pack_bf16x2(a0[i].z, a0[i].w);
            av.z = pack_bf16x2(a1[i].x, a1[i].y);
            av.w = pack_bf16x2(a1[i].z, a1[i].w);
            *(uint4*)&Atile[row * LDT + ach * 8] = av;

            const float s0 = sc[i];
            unsigned int wv[4] = {(unsigned int)wL[i].x, (unsigned int)wL[i].y,
                                  (unsigned int)wL[i].z, (unsigned int)wL[i].w};
            unsigned int od[4];
#pragma unroll
            for (int j = 0; j < 4; ++j) {
                const unsigned int pair = T2[wv[j] & 0xFFu];
                const float fe = __uint_as_float(pair << 16) * s0;           // k even (hi nibble)
                const float fo = __uint_as_float(pair & 0xFFFF0000u) * s0;   // k odd  (lo nibble)
                od[j] = pack_bf16x2(fe, fo);
            }
            uint4 ov; ov.x = od[0]; ov.y = od[1]; ov.z = od[2]; ov.w = od[3];
            *(uint4*)&Btile[row * LDT + ach * 8] = ov;
        }
        __syncthreads();

        // ---- MFMA over the K-tile (2 k-steps of 32) ----
#pragma unroll
        for (int k2 = 0; k2 < 2; ++k2) {
            const int ks = k2 * 32 + (lane >> 4) * 8;
            short8 af[4], bfv[4];
#pragma unroll
            for (int i = 0; i < 4; ++i)
                af[i] = *(const short8*)&Atile[(wm + i * 16 + (lane & 15)) * LDT + ks];
#pragma unroll
            for (int j = 0; j < 4; ++j)
                bfv[j] = *(const short8*)&Btile[(wn + j * 16 + (lane & 15)) * LDT + ks];
#pragma unroll
            for (int i = 0; i < 4; ++i)
#pragma unroll
                for (int j = 0; j < 4; ++j)
                    acc[i][j] = __builtin_amdgcn_mfma_f32_16x16x32_bf16(
                        af[i], bfv[j], acc[i][j], 0, 0, 0);
        }
        __syncthreads();
    }

    // ---- epilogue: D layout col = lane&15, row = (lane>>4)*4 + reg; f32 out ----
#pragma unroll
    for (int j = 0; j < 4; ++j) {
        const int col = n0 + wn + j * 16 + (lane & 15);
        const float bj = Bias[col];
#pragma unroll
        for (int i = 0; i < 4; ++i) {
            const int rowb = m0 + wm + i * 16 + ((lane >> 4) << 2);
#pragma unroll
            for (int r = 0; r < 4; ++r) {
                Out[(size_t)(rowb + r) * O_DIM + col] = acc[i][j][r] + bj;
            }
        }
    }
}

extern "C" void kernel_launch(void* const* d_in, const int* in_sizes, int n_in,
                              void* d_out, int out_size, void* d_ws, size_t ws_size,
                              hipStream_t stream) {
    const float* X    = (const float*)d_in[0];
    const int*   Wp   = (const int*)d_in[1];
    const float* Smax = (const float*)d_in[2];
    const float* Bias = (const float*)d_in[3];
    float*       Out  = (float*)d_out;

    const int M = in_sizes[0] / K_DIM;   // 4096
    dim3 grid(M / BM, O_DIM / BN);       // (32, 86), m-tile fastest
    nf4_linear_kernel<<<grid, dim3(256), 0, stream>>>(X, Wp, Smax, Bias, Out, M);
}